// Round 9
// baseline (366.064 us; speedup 1.0000x reference)
//
#include <hip/hip_runtime.h>
#include <hip/hip_bf16.h>

// Problem constants (match reference)
constexpr int cN = 50000;
constexpr int cE = 800000;
constexpr int cNUM_CLASSES = 40;
constexpr int cFEAT_DIM = 256;
constexpr int cFEAT_HID = 64;
constexpr int cDEG_HID = 32;
constexpr int cHID = 128;
constexpr int cIN_CH = cNUM_CLASSES + cFEAT_HID + cDEG_HID; // 136
constexpr int cKPAD = 160;              // IN_CH padded to multiple of 32
constexpr int cMAX_DEG = 256;

// LDS-histogram CSR build parameters
constexpr int cNCHUNK = 128;            // edge chunks (= copies per histogram)
constexpr int cCHUNK  = cE / cNCHUNK;   // 6250 edges per chunk (exact)
constexpr int cWORDS  = cN / 2;         // 25000 packed u16-pair words per histogram
constexpr int cHWORDS = cWORDS / 2;     // 12500 words per node-range half (50 KB LDS)
constexpr int cSCANB  = (cWORDS + 255) / 256; // 98 blocks for mega_scan

typedef unsigned short ushort8_t __attribute__((ext_vector_type(8)));
typedef short short8_t __attribute__((ext_vector_type(8)));
typedef float float4_t __attribute__((ext_vector_type(4)));

__device__ __forceinline__ unsigned short f2bf(float f) {
    unsigned u = __builtin_bit_cast(unsigned, f);
    u += 0x7fff + ((u >> 16) & 1); // RNE
    return (unsigned short)(u >> 16);
}
__device__ __forceinline__ float bf2f(unsigned short s) {
    unsigned u = ((unsigned)s) << 16;
    return __builtin_bit_cast(float, u);
}
__device__ __forceinline__ float bflo(unsigned p) { return bf2f((unsigned short)(p & 0xFFFFu)); }
__device__ __forceinline__ float bfhi(unsigned p) { return bf2f((unsigned short)(p >> 16)); }

// ---------------- prep: LDS histograms (blocks 0..511) + weight convert (blocks 512+) ----------------
__global__ __launch_bounds__(256) void prep_kernel(const int* __restrict__ edge,
                                                   unsigned* __restrict__ partial,
                                                   const float* __restrict__ Wf,
                                                   const float* __restrict__ W1,
                                                   const float* __restrict__ W2,
                                                   const float* __restrict__ W3,
                                                   unsigned short* __restrict__ Wtf,
                                                   unsigned short* __restrict__ Wt1,
                                                   unsigned short* __restrict__ Wt2,
                                                   unsigned short* __restrict__ Wt3) {
    __shared__ unsigned lds[cHWORDS];
    const int b = blockIdx.x, tid = threadIdx.x;
    if (b < 512) {
        const int cb = b & (cNCHUNK - 1);
        const int half = (b >> 7) & 1;
        const int which = b >> 8;
        for (int i = tid; i < cHWORDS; i += 256) lds[i] = 0;
        __syncthreads();
        const int* ids = edge + (size_t)which * cE + (size_t)cb * cCHUNK;
        const int lo = half * (cN / 2), hi = lo + cN / 2;
        const int wbase = half * cHWORDS;
        for (int i = tid; i < cCHUNK; i += 256) {
            int v = ids[i];
            if (v >= lo && v < hi)
                atomicAdd(&lds[(v >> 1) - wbase], 1u << ((v & 1) * 16));
        }
        __syncthreads();
        unsigned* outp = partial + ((size_t)which * cNCHUNK + cb) * cWORDS + wbase;
        for (int i = tid; i < cHWORDS; i += 256) outp[i] = lds[i];
        return;
    }
    int i = (b - 512) * 256 + tid;
    if (i < 16384) {
        int n = i >> 8, k = i & 255;
        Wtf[i] = f2bf(Wf[k * cFEAT_HID + n]);
        return;
    }
    i -= 16384;
    if (i < 128 * cKPAD) {
        int n = i / cKPAD, k = i - n * cKPAD;
        Wt1[i] = (k < cIN_CH) ? f2bf(W1[k * cHID + n]) : 0;
        return;
    }
    i -= 128 * cKPAD;
    if (i < 128 * 128) {
        int n = i >> 7, k = i & 127;
        Wt2[i] = f2bf(W2[k * cHID + n]);
        return;
    }
    i -= 128 * 128;
    if (i < 48 * 128) {
        int n = i >> 7, k = i & 127;
        Wt3[i] = (n < cNUM_CLASSES) ? f2bf(W3[k * cNUM_CLASSES + n]) : 0;
    }
}

// ---------------- mega_scan: merge copies, chunk-prefix rewrite, counts, rowptr, dinv ----------------
__global__ __launch_bounds__(256) void mega_scan_kernel(unsigned* __restrict__ partial,
                                                        int* __restrict__ count_src,
                                                        int* __restrict__ count_dst,
                                                        int* __restrict__ rowptr,
                                                        float* __restrict__ dinv,
                                                        int* __restrict__ desc) {
    const int b = blockIdx.x, tid = threadIdx.x;
    const int w = b * 256 + tid;
    unsigned slo = 0, shi = 0, plo = 0, phi = 0;
    if (w < cWORDS) {
        const unsigned* ps = partial + w;
        for (int c = 0; c < cNCHUNK; ++c) {
            unsigned v = ps[(size_t)c * cWORDS];
            slo += v & 0xFFFFu; shi += v >> 16;
        }
        *(int2*)&count_src[2 * w] = make_int2((int)slo, (int)shi);
        unsigned* pd = partial + (size_t)cNCHUNK * cWORDS + w;
        for (int c = 0; c < cNCHUNK; ++c) {
            unsigned v = pd[(size_t)c * cWORDS];
            pd[(size_t)c * cWORDS] = plo | (phi << 16);   // per-chunk prefix (fits u16)
            plo += v & 0xFFFFu; phi += v >> 16;
        }
        *(int2*)&count_dst[2 * w] = make_int2((int)plo, (int)phi);
    }
    __shared__ int s[256];
    int tot = (int)(plo + phi);
    s[tid] = tot;
    __syncthreads();
    #pragma unroll
    for (int off = 1; off < 256; off <<= 1) {
        int t = (tid >= off) ? s[tid - off] : 0;
        __syncthreads();
        s[tid] += t;
        __syncthreads();
    }
    int ex_local = s[tid] - tot;
    int block_total = s[255];
    if (tid == 0) atomicExch(&desc[b], block_total + 1);
    if (tid < b) {
        int v;
        do { v = atomicAdd(&desc[tid], 0); } while (v == 0);
        s[tid] = v - 1;
    }
    __syncthreads();
    if (tid >= b) s[tid] = 0;
    __syncthreads();
    #pragma unroll
    for (int off = 128; off > 0; off >>= 1) {
        if (tid < off) s[tid] += s[tid + off];
        __syncthreads();
    }
    int base = s[0] + ex_local;
    if (w < cWORDS) {
        rowptr[2 * w]     = base;
        rowptr[2 * w + 1] = base + (int)plo;
        dinv[2 * w]     = rsqrtf((float)(plo + 1));
        dinv[2 * w + 1] = rsqrtf((float)(phi + 1));
    }
    if (b == 0 && tid == 0) rowptr[cN] = cE;
}

// ---------------- deterministic scatter (no global atomics) ----------------
__global__ __launch_bounds__(256) void scatter2_kernel(const int* __restrict__ edge,
                                                       const unsigned* __restrict__ partial,
                                                       const int* __restrict__ rowptr,
                                                       int* __restrict__ adj) {
    __shared__ unsigned lds[cHWORDS];
    const int b = blockIdx.x, tid = threadIdx.x;
    const int cb = b & (cNCHUNK - 1);
    const int half = b >> 7;
    const int wbase = half * cHWORDS;
    const unsigned* pp = partial + ((size_t)cNCHUNK + cb) * cWORDS + wbase;
    for (int i = tid; i < cHWORDS; i += 256) lds[i] = pp[i];
    __syncthreads();
    const int* srcs = edge + (size_t)cb * cCHUNK;
    const int* dsts = edge + cE + (size_t)cb * cCHUNK;
    const int lo = half * (cN / 2), hi = lo + cN / 2;
    for (int i = tid; i < cCHUNK; i += 256) {
        int d = dsts[i];
        if (d >= lo && d < hi) {
            int sh = (d & 1) * 16;
            unsigned old = atomicAdd(&lds[(d >> 1) - wbase], 1u << sh);
            int off = (int)((old >> sh) & 0xFFFFu);
            adj[rowptr[d] + off] = srcs[i];
        }
    }
}

// ---------------- frontend: xb[:,0:40]=bf16(logits); xb[:,104:136]=deg_emb; xb[:,136:160]=0 ----------------
__global__ __launch_bounds__(256) void frontend_kernel(const float* __restrict__ logits,
                                                       const int* __restrict__ count_src,
                                                       const int* __restrict__ count_dst,
                                                       const float* __restrict__ deg_table,
                                                       unsigned short* __restrict__ xb) {
    constexpr int W = cNUM_CLASSES + cDEG_HID + 24; // 96 columns handled per row
    int idx = blockIdx.x * 256 + threadIdx.x;
    if (idx >= cN * W) return;
    int i = idx / W;
    int j = idx - i * W;
    if (j < cNUM_CLASSES) {
        xb[(size_t)i * cKPAD + j] = f2bf(logits[(size_t)i * cNUM_CLASSES + j]);
    } else {
        int jj = j - cNUM_CLASSES; // 0..55 -> cols 104..159
        unsigned short v = 0;
        if (jj < cDEG_HID) {
            int deg = count_src[i] + count_dst[i];
            if (deg > cMAX_DEG - 1) deg = cMAX_DEG - 1;
            v = f2bf(deg_table[deg * cDEG_HID + jj]);
        }
        xb[(size_t)i * cKPAD + cNUM_CLASSES + cFEAT_HID + jj] = v;
    }
}

// ---------------- MFMA GEMM: out[m][n] = A[m][:K] @ Bt[n][:K]^T (+bias), bf16 out ----------------
template <int ASTR, int KTOT, int NT, int OSTR, int OOFF, int OUTC, bool AFP32, bool BIAS>
__global__ __launch_bounds__(256) void mfma_gemm(const void* __restrict__ Av,
                                                 const unsigned short* __restrict__ Bt,
                                                 const float* __restrict__ bias,
                                                 unsigned short* __restrict__ out) {
    __shared__ unsigned short As[64 * 32];      // As[m][k] stride 32
    __shared__ unsigned short Bs[NT * 16 * 32]; // Bs[n][k] stride 32

    const int tid = threadIdx.x;
    const int wave = tid >> 6;
    const int lane = tid & 63;
    const int m15 = lane & 15;
    const int q = lane >> 4;
    const int rowbase = blockIdx.x * 64;

    float4_t acc[NT];
    #pragma unroll
    for (int t = 0; t < NT; ++t) acc[t] = (float4_t){0.f, 0.f, 0.f, 0.f};

    const int arow = tid >> 2;            // 0..63
    const int akq = (tid & 3) * 8;        // 0,8,16,24
    int gr = rowbase + arow;
    if (gr > cN - 1) gr = cN - 1;

    for (int k0 = 0; k0 < KTOT; k0 += 32) {
        if constexpr (AFP32) {
            const float* ap = (const float*)Av + (size_t)gr * ASTR + k0 + akq;
            float4 v0 = *(const float4*)ap;
            float4 v1 = *(const float4*)(ap + 4);
            ushort8_t o = { f2bf(v0.x), f2bf(v0.y), f2bf(v0.z), f2bf(v0.w),
                            f2bf(v1.x), f2bf(v1.y), f2bf(v1.z), f2bf(v1.w) };
            *(ushort8_t*)&As[arow * 32 + akq] = o;
        } else {
            const unsigned short* ap = (const unsigned short*)Av + (size_t)gr * ASTR + k0 + akq;
            *(ushort8_t*)&As[arow * 32 + akq] = *(const ushort8_t*)ap;
        }
        for (int i = tid; i < NT * 64; i += 256) {
            int n = i >> 2;
            int kq = (i & 3) * 8;
            *(ushort8_t*)&Bs[n * 32 + kq] = *(const ushort8_t*)&Bt[(size_t)n * KTOT + k0 + kq];
        }
        __syncthreads();

        short8_t a = *(const short8_t*)&As[(wave * 16 + m15) * 32 + q * 8];
        #pragma unroll
        for (int t = 0; t < NT; ++t) {
            short8_t b = *(const short8_t*)&Bs[(t * 16 + m15) * 32 + q * 8];
            acc[t] = __builtin_amdgcn_mfma_f32_16x16x32_bf16(a, b, acc[t], 0, 0, 0);
        }
        __syncthreads();
    }

    #pragma unroll
    for (int t = 0; t < NT; ++t) {
        int col = t * 16 + m15;
        if (OUTC % 16 != 0 && col >= OUTC) continue;
        float bv = BIAS ? bias[col] : 0.f;
        #pragma unroll
        for (int r = 0; r < 4; ++r) {
            int row = rowbase + wave * 16 + q * 4 + r;
            if (row < cN)
                out[(size_t)row * OSTR + OOFF + col] = f2bf(acc[t][r] + bv);
        }
    }
}

// ---------------- GCN aggregate, 128 ch, ONE ROW PER WAVE (lane = channel pair) ----------------
template <bool RELU>
__global__ __launch_bounds__(256) void agg_w128(const unsigned short* __restrict__ t,
                                                const int* __restrict__ rowptr,
                                                const int* __restrict__ adj,
                                                const float* __restrict__ dinv,
                                                const float* __restrict__ b,
                                                unsigned short* __restrict__ outb) {
    const int tid = threadIdx.x;
    const int wave = tid >> 6;
    const int lane = tid & 63;
    const int row = blockIdx.x * 4 + wave;
    if (row >= cN) return;
    const int c = lane * 2;
    const float di = dinv[row];
    int e = rowptr[row];
    const int end = rowptr[row + 1];
    float a00 = 0.f, a01 = 0.f, a10 = 0.f, a11 = 0.f;
    for (; e + 1 < end; e += 2) {
        int j0 = adj[e], j1 = adj[e + 1];
        float v0 = dinv[j0], v1 = dinv[j1];
        unsigned p0 = *(const unsigned*)&t[(size_t)j0 * cHID + c];
        unsigned p1 = *(const unsigned*)&t[(size_t)j1 * cHID + c];
        a00 += v0 * bflo(p0); a01 += v0 * bfhi(p0);
        a10 += v1 * bflo(p1); a11 += v1 * bfhi(p1);
    }
    if (e < end) {
        int j0 = adj[e];
        float v0 = dinv[j0];
        unsigned p0 = *(const unsigned*)&t[(size_t)j0 * cHID + c];
        a00 += v0 * bflo(p0); a01 += v0 * bfhi(p0);
    }
    unsigned ps = *(const unsigned*)&t[(size_t)row * cHID + c];
    const float d2 = di * di;
    float r0 = di * (a00 + a10) + d2 * bflo(ps) + b[c];
    float r1 = di * (a01 + a11) + d2 * bfhi(ps) + b[c + 1];
    if (RELU) { r0 = fmaxf(r0, 0.f); r1 = fmaxf(r1, 0.f); }
    unsigned o = (unsigned)f2bf(r0) | ((unsigned)f2bf(r1) << 16);
    *(unsigned*)&outb[(size_t)row * cHID + c] = o;
}

// ---------------- GCN aggregate, 40 ch, TWO ROWS PER WAVE (fp32 out, final) ----------------
__global__ __launch_bounds__(256) void agg_w40(const unsigned short* __restrict__ t,
                                               const int* __restrict__ rowptr,
                                               const int* __restrict__ adj,
                                               const float* __restrict__ dinv,
                                               const float* __restrict__ b,
                                               float* __restrict__ out) {
    const int tid = threadIdx.x;
    const int wave = tid >> 6;
    const int lane = tid & 63;
    const int half = lane >> 5;       // 2 rows per wave
    const int l = lane & 31;
    const int row = blockIdx.x * 8 + wave * 2 + half;
    if (row >= cN) return;
    const int c = l * 2;
    if (c >= cNUM_CLASSES) return;    // lanes 20..31 of each half idle
    const float di = dinv[row];
    int e = rowptr[row];
    const int end = rowptr[row + 1];
    float a00 = 0.f, a01 = 0.f, a10 = 0.f, a11 = 0.f;
    for (; e + 1 < end; e += 2) {
        int j0 = adj[e], j1 = adj[e + 1];
        float v0 = dinv[j0], v1 = dinv[j1];
        unsigned p0 = *(const unsigned*)&t[(size_t)j0 * cNUM_CLASSES + c];
        unsigned p1 = *(const unsigned*)&t[(size_t)j1 * cNUM_CLASSES + c];
        a00 += v0 * bflo(p0); a01 += v0 * bfhi(p0);
        a10 += v1 * bflo(p1); a11 += v1 * bfhi(p1);
    }
    if (e < end) {
        int j0 = adj[e];
        float v0 = dinv[j0];
        unsigned p0 = *(const unsigned*)&t[(size_t)j0 * cNUM_CLASSES + c];
        a00 += v0 * bflo(p0); a01 += v0 * bfhi(p0);
    }
    unsigned ps = *(const unsigned*)&t[(size_t)row * cNUM_CLASSES + c];
    const float d2 = di * di;
    float r0 = di * (a00 + a10) + d2 * bflo(ps) + b[c];
    float r1 = di * (a01 + a11) + d2 * bfhi(ps) + b[c + 1];
    *(float2*)&out[(size_t)row * cNUM_CLASSES + c] = make_float2(r0, r1);
}

extern "C" void kernel_launch(void* const* d_in, const int* in_sizes, int n_in,
                              void* d_out, int out_size, void* d_ws, size_t ws_size,
                              hipStream_t stream) {
    const float* logits    = (const float*)d_in[0];
    const float* features  = (const float*)d_in[1];
    const int*   edge      = (const int*)d_in[2];
    const float* Wf        = (const float*)d_in[3];
    const float* bf        = (const float*)d_in[4];
    const float* deg_table = (const float*)d_in[5];
    const float* W1        = (const float*)d_in[6];
    const float* b1        = (const float*)d_in[7];
    const float* W2        = (const float*)d_in[8];
    const float* b2        = (const float*)d_in[9];
    const float* W3        = (const float*)d_in[10];
    const float* b3        = (const float*)d_in[11];
    float* out = (float*)d_out;

    // workspace carve-up (16B-aligned sections)
    int* count_src = (int*)d_ws;                 // N
    int* count_dst = count_src + cN;             // N
    int* rowptr    = count_dst + cN;             // N+1 (padded)
    int* adj       = rowptr + cN + 16;           // E
    int* desc      = adj + cE;                   // 128
    float* dinv    = (float*)(desc + 128);       // N
    unsigned short* xb  = (unsigned short*)(dinv + cN);            // N*160 bf16
    unsigned short* tb  = xb + (size_t)cN * cKPAD;                 // N*128 bf16
    unsigned short* hb  = tb + (size_t)cN * cHID;                  // N*128 bf16
    unsigned short* Wtf = hb + (size_t)cN * cHID;                  // 64*256
    unsigned short* Wt1 = Wtf + 64 * 256;                          // 128*160
    unsigned short* Wt2 = Wt1 + 128 * cKPAD;                       // 128*128
    unsigned short* Wt3 = Wt2 + 128 * 128;                         // 48*128
    unsigned* partial = (unsigned*)(Wt3 + 48 * 128);               // 2*128*25000 u32

    hipMemsetAsync(desc, 0, 128 * sizeof(int), stream);

    // histograms + weight conversion (one launch)
    constexpr int WTOT = 16384 + 128 * cKPAD + 128 * 128 + 48 * 128;
    constexpr int WBLK = (WTOT + 255) / 256;
    prep_kernel<<<512 + WBLK, 256, 0, stream>>>(edge, partial, Wf, W1, W2, W3, Wtf, Wt1, Wt2, Wt3);

    // merged scan: counts, chunk-prefix rewrite, rowptr, dinv (one launch, parallel lookback)
    mega_scan_kernel<<<cSCANB, 256, 0, stream>>>(partial, count_src, count_dst, rowptr, dinv, desc);

    // CSR scatter (no global atomics)
    scatter2_kernel<<<256, 256, 0, stream>>>(edge, partial, rowptr, adj);

    // frontend -> xb (logits + degree embedding + zero pad)
    frontend_kernel<<<(cN * 96 + 255) / 256, 256, 0, stream>>>(logits, count_src, count_dst, deg_table, xb);

    constexpr int MB = (cN + 63) / 64; // 782

    // featlin: xb[:,40:104] = bf16(features @ Wf + bf)
    mfma_gemm<cFEAT_DIM, 256, 4, cKPAD, cNUM_CLASSES, 64, true, true>
        <<<MB, 256, 0, stream>>>(features, Wtf, bf, xb);

    // conv1
    mfma_gemm<cKPAD, cKPAD, 8, cHID, 0, cHID, false, false>
        <<<MB, 256, 0, stream>>>(xb, Wt1, nullptr, tb);
    agg_w128<true><<<(cN + 3) / 4, 256, 0, stream>>>(tb, rowptr, adj, dinv, b1, hb);

    // conv2
    mfma_gemm<cHID, cHID, 8, cHID, 0, cHID, false, false>
        <<<MB, 256, 0, stream>>>(hb, Wt2, nullptr, tb);
    agg_w128<true><<<(cN + 3) / 4, 256, 0, stream>>>(tb, rowptr, adj, dinv, b2, hb);

    // conv3
    mfma_gemm<cHID, cHID, 3, cNUM_CLASSES, 0, cNUM_CLASSES, false, false>
        <<<MB, 256, 0, stream>>>(hb, Wt3, nullptr, tb);
    agg_w40<<<(cN + 7) / 8, 256, 0, stream>>>(tb, rowptr, adj, dinv, b3, out);
}

// Round 10
// 341.152 us; speedup vs baseline: 1.0730x; 1.0730x over previous
//
#include <hip/hip_runtime.h>
#include <hip/hip_bf16.h>

// Problem constants (match reference)
constexpr int cN = 50000;
constexpr int cE = 800000;
constexpr int cNUM_CLASSES = 40;
constexpr int cFEAT_DIM = 256;
constexpr int cFEAT_HID = 64;
constexpr int cDEG_HID = 32;
constexpr int cHID = 128;
constexpr int cIN_CH = cNUM_CLASSES + cFEAT_HID + cDEG_HID; // 136
constexpr int cKPAD = 160;              // IN_CH padded to multiple of 32
constexpr int cMAX_DEG = 256;

// LDS-histogram CSR build parameters
constexpr int cNCHUNK = 128;            // edge chunks (= copies per histogram)
constexpr int cCHUNK  = cE / cNCHUNK;   // 6250 edges per chunk (exact)
constexpr int cWORDS  = cN / 2;         // 25000 packed u16-pair words per histogram
constexpr int cHWORDS = cWORDS / 2;     // 12500 words per node-range half (50 KB LDS)
constexpr int cSCANB  = (cWORDS + 255) / 256; // 98 blocks for mega_scan

typedef unsigned short ushort8_t __attribute__((ext_vector_type(8)));
typedef unsigned short ushort4_t __attribute__((ext_vector_type(4)));
typedef short short8_t __attribute__((ext_vector_type(8)));
typedef float float4_t __attribute__((ext_vector_type(4)));

__device__ __forceinline__ unsigned short f2bf(float f) {
    unsigned u = __builtin_bit_cast(unsigned, f);
    u += 0x7fff + ((u >> 16) & 1); // RNE
    return (unsigned short)(u >> 16);
}
__device__ __forceinline__ float bf2f(unsigned short s) {
    unsigned u = ((unsigned)s) << 16;
    return __builtin_bit_cast(float, u);
}

// ---------------- prep: LDS histograms (blocks 0..511) + weight convert (blocks 512+) ----------------
__global__ __launch_bounds__(256) void prep_kernel(const int* __restrict__ edge,
                                                   unsigned* __restrict__ partial,
                                                   const float* __restrict__ Wf,
                                                   const float* __restrict__ W1,
                                                   const float* __restrict__ W2,
                                                   const float* __restrict__ W3,
                                                   unsigned short* __restrict__ Wtf,
                                                   unsigned short* __restrict__ Wt1,
                                                   unsigned short* __restrict__ Wt2,
                                                   unsigned short* __restrict__ Wt3) {
    __shared__ unsigned lds[cHWORDS];
    const int b = blockIdx.x, tid = threadIdx.x;
    if (b < 512) {
        const int cb = b & (cNCHUNK - 1);
        const int half = (b >> 7) & 1;
        const int which = b >> 8;
        for (int i = tid; i < cHWORDS; i += 256) lds[i] = 0;
        __syncthreads();
        const int* ids = edge + (size_t)which * cE + (size_t)cb * cCHUNK;
        const int lo = half * (cN / 2), hi = lo + cN / 2;
        const int wbase = half * cHWORDS;
        for (int i = tid; i < cCHUNK; i += 256) {
            int v = ids[i];
            if (v >= lo && v < hi)
                atomicAdd(&lds[(v >> 1) - wbase], 1u << ((v & 1) * 16));
        }
        __syncthreads();
        unsigned* outp = partial + ((size_t)which * cNCHUNK + cb) * cWORDS + wbase;
        for (int i = tid; i < cHWORDS; i += 256) outp[i] = lds[i];
        return;
    }
    int i = (b - 512) * 256 + tid;
    if (i < 16384) {
        int n = i >> 8, k = i & 255;
        Wtf[i] = f2bf(Wf[k * cFEAT_HID + n]);
        return;
    }
    i -= 16384;
    if (i < 128 * cKPAD) {
        int n = i / cKPAD, k = i - n * cKPAD;
        Wt1[i] = (k < cIN_CH) ? f2bf(W1[k * cHID + n]) : 0;
        return;
    }
    i -= 128 * cKPAD;
    if (i < 128 * 128) {
        int n = i >> 7, k = i & 127;
        Wt2[i] = f2bf(W2[k * cHID + n]);
        return;
    }
    i -= 128 * 128;
    if (i < 48 * 128) {
        int n = i >> 7, k = i & 127;
        Wt3[i] = (n < cNUM_CLASSES) ? f2bf(W3[k * cNUM_CLASSES + n]) : 0;
    }
}

// ---------------- mega_scan: merge copies, chunk-prefix rewrite, counts, rowptr, dinv ----------------
__global__ __launch_bounds__(256) void mega_scan_kernel(unsigned* __restrict__ partial,
                                                        int* __restrict__ count_src,
                                                        int* __restrict__ count_dst,
                                                        int* __restrict__ rowptr,
                                                        float* __restrict__ dinv,
                                                        int* __restrict__ desc) {
    const int b = blockIdx.x, tid = threadIdx.x;
    const int w = b * 256 + tid;
    unsigned slo = 0, shi = 0, plo = 0, phi = 0;
    if (w < cWORDS) {
        const unsigned* ps = partial + w;
        for (int c = 0; c < cNCHUNK; ++c) {
            unsigned v = ps[(size_t)c * cWORDS];
            slo += v & 0xFFFFu; shi += v >> 16;
        }
        *(int2*)&count_src[2 * w] = make_int2((int)slo, (int)shi);
        unsigned* pd = partial + (size_t)cNCHUNK * cWORDS + w;
        for (int c = 0; c < cNCHUNK; ++c) {
            unsigned v = pd[(size_t)c * cWORDS];
            pd[(size_t)c * cWORDS] = plo | (phi << 16);   // per-chunk prefix (fits u16)
            plo += v & 0xFFFFu; phi += v >> 16;
        }
        *(int2*)&count_dst[2 * w] = make_int2((int)plo, (int)phi);
    }
    __shared__ int s[256];
    int tot = (int)(plo + phi);
    s[tid] = tot;
    __syncthreads();
    #pragma unroll
    for (int off = 1; off < 256; off <<= 1) {
        int t = (tid >= off) ? s[tid - off] : 0;
        __syncthreads();
        s[tid] += t;
        __syncthreads();
    }
    int ex_local = s[tid] - tot;
    int block_total = s[255];
    if (tid == 0) atomicExch(&desc[b], block_total + 1);
    if (tid < b) {
        int v;
        do { v = atomicAdd(&desc[tid], 0); } while (v == 0);
        s[tid] = v - 1;
    }
    __syncthreads();
    if (tid >= b) s[tid] = 0;
    __syncthreads();
    #pragma unroll
    for (int off = 128; off > 0; off >>= 1) {
        if (tid < off) s[tid] += s[tid + off];
        __syncthreads();
    }
    int base = s[0] + ex_local;
    if (w < cWORDS) {
        rowptr[2 * w]     = base;
        rowptr[2 * w + 1] = base + (int)plo;
        dinv[2 * w]     = rsqrtf((float)(plo + 1));
        dinv[2 * w + 1] = rsqrtf((float)(phi + 1));
    }
    if (b == 0 && tid == 0) rowptr[cN] = cE;
}

// ---------------- deterministic scatter (no global atomics) ----------------
__global__ __launch_bounds__(256) void scatter2_kernel(const int* __restrict__ edge,
                                                       const unsigned* __restrict__ partial,
                                                       const int* __restrict__ rowptr,
                                                       int* __restrict__ adj) {
    __shared__ unsigned lds[cHWORDS];
    const int b = blockIdx.x, tid = threadIdx.x;
    const int cb = b & (cNCHUNK - 1);
    const int half = b >> 7;
    const int wbase = half * cHWORDS;
    const unsigned* pp = partial + ((size_t)cNCHUNK + cb) * cWORDS + wbase;
    for (int i = tid; i < cHWORDS; i += 256) lds[i] = pp[i];
    __syncthreads();
    const int* srcs = edge + (size_t)cb * cCHUNK;
    const int* dsts = edge + cE + (size_t)cb * cCHUNK;
    const int lo = half * (cN / 2), hi = lo + cN / 2;
    for (int i = tid; i < cCHUNK; i += 256) {
        int d = dsts[i];
        if (d >= lo && d < hi) {
            int sh = (d & 1) * 16;
            unsigned old = atomicAdd(&lds[(d >> 1) - wbase], 1u << sh);
            int off = (int)((old >> sh) & 0xFFFFu);
            adj[rowptr[d] + off] = srcs[i];
        }
    }
}

// ---------------- frontend: xb[:,0:40]=bf16(logits); xb[:,104:136]=deg_emb; xb[:,136:160]=0 ----------------
__global__ __launch_bounds__(256) void frontend_kernel(const float* __restrict__ logits,
                                                       const int* __restrict__ count_src,
                                                       const int* __restrict__ count_dst,
                                                       const float* __restrict__ deg_table,
                                                       unsigned short* __restrict__ xb) {
    constexpr int W = cNUM_CLASSES + cDEG_HID + 24; // 96 columns handled per row
    int idx = blockIdx.x * 256 + threadIdx.x;
    if (idx >= cN * W) return;
    int i = idx / W;
    int j = idx - i * W;
    if (j < cNUM_CLASSES) {
        xb[(size_t)i * cKPAD + j] = f2bf(logits[(size_t)i * cNUM_CLASSES + j]);
    } else {
        int jj = j - cNUM_CLASSES; // 0..55 -> cols 104..159
        unsigned short v = 0;
        if (jj < cDEG_HID) {
            int deg = count_src[i] + count_dst[i];
            if (deg > cMAX_DEG - 1) deg = cMAX_DEG - 1;
            v = f2bf(deg_table[deg * cDEG_HID + jj]);
        }
        xb[(size_t)i * cKPAD + cNUM_CLASSES + cFEAT_HID + jj] = v;
    }
}

// ---------------- MFMA GEMM: out[m][n] = A[m][:K] @ Bt[n][:K]^T (+bias), bf16 out ----------------
template <int ASTR, int KTOT, int NT, int OSTR, int OOFF, int OUTC, bool AFP32, bool BIAS>
__global__ __launch_bounds__(256) void mfma_gemm(const void* __restrict__ Av,
                                                 const unsigned short* __restrict__ Bt,
                                                 const float* __restrict__ bias,
                                                 unsigned short* __restrict__ out) {
    __shared__ unsigned short As[64 * 32];      // As[m][k] stride 32
    __shared__ unsigned short Bs[NT * 16 * 32]; // Bs[n][k] stride 32

    const int tid = threadIdx.x;
    const int wave = tid >> 6;
    const int lane = tid & 63;
    const int m15 = lane & 15;
    const int q = lane >> 4;
    const int rowbase = blockIdx.x * 64;

    float4_t acc[NT];
    #pragma unroll
    for (int t = 0; t < NT; ++t) acc[t] = (float4_t){0.f, 0.f, 0.f, 0.f};

    const int arow = tid >> 2;            // 0..63
    const int akq = (tid & 3) * 8;        // 0,8,16,24
    int gr = rowbase + arow;
    if (gr > cN - 1) gr = cN - 1;

    for (int k0 = 0; k0 < KTOT; k0 += 32) {
        if constexpr (AFP32) {
            const float* ap = (const float*)Av + (size_t)gr * ASTR + k0 + akq;
            float4 v0 = *(const float4*)ap;
            float4 v1 = *(const float4*)(ap + 4);
            ushort8_t o = { f2bf(v0.x), f2bf(v0.y), f2bf(v0.z), f2bf(v0.w),
                            f2bf(v1.x), f2bf(v1.y), f2bf(v1.z), f2bf(v1.w) };
            *(ushort8_t*)&As[arow * 32 + akq] = o;
        } else {
            const unsigned short* ap = (const unsigned short*)Av + (size_t)gr * ASTR + k0 + akq;
            *(ushort8_t*)&As[arow * 32 + akq] = *(const ushort8_t*)ap;
        }
        for (int i = tid; i < NT * 64; i += 256) {
            int n = i >> 2;
            int kq = (i & 3) * 8;
            *(ushort8_t*)&Bs[n * 32 + kq] = *(const ushort8_t*)&Bt[(size_t)n * KTOT + k0 + kq];
        }
        __syncthreads();

        short8_t a = *(const short8_t*)&As[(wave * 16 + m15) * 32 + q * 8];
        #pragma unroll
        for (int t = 0; t < NT; ++t) {
            short8_t b = *(const short8_t*)&Bs[(t * 16 + m15) * 32 + q * 8];
            acc[t] = __builtin_amdgcn_mfma_f32_16x16x32_bf16(a, b, acc[t], 0, 0, 0);
        }
        __syncthreads();
    }

    #pragma unroll
    for (int t = 0; t < NT; ++t) {
        int col = t * 16 + m15;
        if (OUTC % 16 != 0 && col >= OUTC) continue;
        float bv = BIAS ? bias[col] : 0.f;
        #pragma unroll
        for (int r = 0; r < 4; ++r) {
            int row = rowbase + wave * 16 + q * 4 + r;
            if (row < cN)
                out[(size_t)row * OSTR + OOFF + col] = f2bf(acc[t][r] + bv);
        }
    }
}

// ---------------- GCN aggregate, 128 ch: one row/wave, 4 edge-groups x 16 lanes, 16B loads ----------------
template <bool RELU>
__global__ __launch_bounds__(256) void agg_g128(const unsigned short* __restrict__ t,
                                                const int* __restrict__ rowptr,
                                                const int* __restrict__ adj,
                                                const float* __restrict__ dinv,
                                                const float* __restrict__ b,
                                                unsigned short* __restrict__ outb) {
    const int tid = threadIdx.x;
    const int wave = tid >> 6;
    const int lane = tid & 63;
    const int g = lane >> 4;          // edge group 0..3
    const int l = lane & 15;          // channel lane
    const int row = blockIdx.x * 4 + wave;
    if (row >= cN) return;
    const int c = l * 8;
    const float di = dinv[row];
    const int beg = rowptr[row], end = rowptr[row + 1];
    float acc[8];
    #pragma unroll
    for (int k = 0; k < 8; ++k) acc[k] = 0.f;
    for (int e = beg; e < end; e += 4) {
        int ee = e + g;
        bool valid = ee < end;
        int j = valid ? adj[ee] : row;    // safe address when masked
        float v = valid ? dinv[j] : 0.f;
        ushort8_t tv = *(const ushort8_t*)&t[(size_t)j * cHID + c];
        #pragma unroll
        for (int k = 0; k < 8; ++k) acc[k] += v * bf2f(tv[k]);
    }
    // combine the 4 edge-groups (lanes differing in bits 4,5)
    #pragma unroll
    for (int k = 0; k < 8; ++k) {
        float a = acc[k];
        a += __shfl_xor(a, 16, 64);
        a += __shfl_xor(a, 32, 64);
        acc[k] = a;
    }
    if (g == 0) {
        ushort8_t ts = *(const ushort8_t*)&t[(size_t)row * cHID + c];
        const float d2 = di * di;
        ushort8_t o;
        #pragma unroll
        for (int k = 0; k < 8; ++k) {
            float r = di * acc[k] + d2 * bf2f(ts[k]) + b[c + k];
            if (RELU) r = fmaxf(r, 0.f);
            o[k] = f2bf(r);
        }
        *(ushort8_t*)&outb[(size_t)row * cHID + c] = o;
    }
}

// ---------------- GCN aggregate, 40 ch: one row/wave, 4 edge-groups x 16 lanes, 8B loads, fp32 out ----------------
__global__ __launch_bounds__(256) void agg_g40(const unsigned short* __restrict__ t,
                                               const int* __restrict__ rowptr,
                                               const int* __restrict__ adj,
                                               const float* __restrict__ dinv,
                                               const float* __restrict__ b,
                                               float* __restrict__ out) {
    const int tid = threadIdx.x;
    const int wave = tid >> 6;
    const int lane = tid & 63;
    const int g = lane >> 4;          // edge group 0..3
    const int l = lane & 15;          // channel lane (0..9 active)
    const int row = blockIdx.x * 4 + wave;
    if (row >= cN) return;
    const int c = l * 4;
    const bool act = c < cNUM_CLASSES;
    const float di = dinv[row];
    const int beg = rowptr[row], end = rowptr[row + 1];
    float acc[4];
    #pragma unroll
    for (int k = 0; k < 4; ++k) acc[k] = 0.f;
    for (int e = beg; e < end; e += 4) {
        int ee = e + g;
        bool valid = (ee < end) && act;
        int j = (ee < end) ? adj[ee] : row;
        float v = valid ? dinv[j] : 0.f;
        int cc = act ? c : 0;
        ushort4_t tv = *(const ushort4_t*)&t[(size_t)j * cNUM_CLASSES + cc];
        #pragma unroll
        for (int k = 0; k < 4; ++k) acc[k] += v * bf2f(tv[k]);
    }
    #pragma unroll
    for (int k = 0; k < 4; ++k) {
        float a = acc[k];
        a += __shfl_xor(a, 16, 64);
        a += __shfl_xor(a, 32, 64);
        acc[k] = a;
    }
    if (g == 0 && act) {
        ushort4_t ts = *(const ushort4_t*)&t[(size_t)row * cNUM_CLASSES + c];
        const float d2 = di * di;
        float4 r;
        r.x = di * acc[0] + d2 * bf2f(ts[0]) + b[c];
        r.y = di * acc[1] + d2 * bf2f(ts[1]) + b[c + 1];
        r.z = di * acc[2] + d2 * bf2f(ts[2]) + b[c + 2];
        r.w = di * acc[3] + d2 * bf2f(ts[3]) + b[c + 3];
        *(float4*)&out[(size_t)row * cNUM_CLASSES + c] = r;
    }
}

extern "C" void kernel_launch(void* const* d_in, const int* in_sizes, int n_in,
                              void* d_out, int out_size, void* d_ws, size_t ws_size,
                              hipStream_t stream) {
    const float* logits    = (const float*)d_in[0];
    const float* features  = (const float*)d_in[1];
    const int*   edge      = (const int*)d_in[2];
    const float* Wf        = (const float*)d_in[3];
    const float* bf        = (const float*)d_in[4];
    const float* deg_table = (const float*)d_in[5];
    const float* W1        = (const float*)d_in[6];
    const float* b1        = (const float*)d_in[7];
    const float* W2        = (const float*)d_in[8];
    const float* b2        = (const float*)d_in[9];
    const float* W3        = (const float*)d_in[10];
    const float* b3        = (const float*)d_in[11];
    float* out = (float*)d_out;

    // workspace carve-up (16B-aligned sections)
    int* count_src = (int*)d_ws;                 // N
    int* count_dst = count_src + cN;             // N
    int* rowptr    = count_dst + cN;             // N+1 (padded)
    int* adj       = rowptr + cN + 16;           // E
    int* desc      = adj + cE;                   // 128
    float* dinv    = (float*)(desc + 128);       // N
    unsigned short* xb  = (unsigned short*)(dinv + cN);            // N*160 bf16
    unsigned short* tb  = xb + (size_t)cN * cKPAD;                 // N*128 bf16
    unsigned short* hb  = tb + (size_t)cN * cHID;                  // N*128 bf16
    unsigned short* Wtf = hb + (size_t)cN * cHID;                  // 64*256
    unsigned short* Wt1 = Wtf + 64 * 256;                          // 128*160
    unsigned short* Wt2 = Wt1 + 128 * cKPAD;                       // 128*128
    unsigned short* Wt3 = Wt2 + 128 * 128;                         // 48*128
    unsigned* partial = (unsigned*)(Wt3 + 48 * 128);               // 2*128*25000 u32

    hipMemsetAsync(desc, 0, 128 * sizeof(int), stream);

    // histograms + weight conversion (one launch)
    constexpr int WTOT = 16384 + 128 * cKPAD + 128 * 128 + 48 * 128;
    constexpr int WBLK = (WTOT + 255) / 256;
    prep_kernel<<<512 + WBLK, 256, 0, stream>>>(edge, partial, Wf, W1, W2, W3, Wtf, Wt1, Wt2, Wt3);

    // merged scan: counts, chunk-prefix rewrite, rowptr, dinv (one launch, parallel lookback)
    mega_scan_kernel<<<cSCANB, 256, 0, stream>>>(partial, count_src, count_dst, rowptr, dinv, desc);

    // CSR scatter (no global atomics)
    scatter2_kernel<<<256, 256, 0, stream>>>(edge, partial, rowptr, adj);

    // frontend -> xb (logits + degree embedding + zero pad)
    frontend_kernel<<<(cN * 96 + 255) / 256, 256, 0, stream>>>(logits, count_src, count_dst, deg_table, xb);

    constexpr int MB = (cN + 63) / 64; // 782

    // featlin: xb[:,40:104] = bf16(features @ Wf + bf)
    mfma_gemm<cFEAT_DIM, 256, 4, cKPAD, cNUM_CLASSES, 64, true, true>
        <<<MB, 256, 0, stream>>>(features, Wtf, bf, xb);

    // conv1
    mfma_gemm<cKPAD, cKPAD, 8, cHID, 0, cHID, false, false>
        <<<MB, 256, 0, stream>>>(xb, Wt1, nullptr, tb);
    agg_g128<true><<<(cN + 3) / 4, 256, 0, stream>>>(tb, rowptr, adj, dinv, b1, hb);

    // conv2
    mfma_gemm<cHID, cHID, 8, cHID, 0, cHID, false, false>
        <<<MB, 256, 0, stream>>>(hb, Wt2, nullptr, tb);
    agg_g128<true><<<(cN + 3) / 4, 256, 0, stream>>>(tb, rowptr, adj, dinv, b2, hb);

    // conv3
    mfma_gemm<cHID, cHID, 3, cNUM_CLASSES, 0, cNUM_CLASSES, false, false>
        <<<MB, 256, 0, stream>>>(hb, Wt3, nullptr, tb);
    agg_g40<<<(cN + 3) / 4, 256, 0, stream>>>(tb, rowptr, adj, dinv, b3, out);
}

// Round 11
// 293.481 us; speedup vs baseline: 1.2473x; 1.1624x over previous
//
#include <hip/hip_runtime.h>
#include <hip/hip_bf16.h>

// Problem constants (match reference)
constexpr int cN = 50000;
constexpr int cE = 800000;
constexpr int cNUM_CLASSES = 40;
constexpr int cFEAT_DIM = 256;
constexpr int cFEAT_HID = 64;
constexpr int cDEG_HID = 32;
constexpr int cHID = 128;
constexpr int cMAX_DEG = 256;
constexpr int cKF = 352;                // fused conv1 K: 40 logits + 256 feat + 32 deg + 24 pad

// LDS-histogram CSR build parameters
constexpr int cNCHUNK = 128;            // edge chunks (= copies per histogram)
constexpr int cCHUNK  = cE / cNCHUNK;   // 6250 edges per chunk (exact)
constexpr int cWORDS  = cN / 2;         // 25000 packed u16-pair words per histogram
constexpr int cHWORDS = cWORDS / 2;     // 12500 words per node-range half (50 KB LDS)
constexpr int cSCANB  = (cWORDS + 255) / 256; // 98 blocks for mega_scan

typedef unsigned short ushort8_t __attribute__((ext_vector_type(8)));
typedef short short8_t __attribute__((ext_vector_type(8)));
typedef float float4_t __attribute__((ext_vector_type(4)));

__device__ __forceinline__ unsigned short f2bf(float f) {
    unsigned u = __builtin_bit_cast(unsigned, f);
    u += 0x7fff + ((u >> 16) & 1); // RNE
    return (unsigned short)(u >> 16);
}
__device__ __forceinline__ float bf2f(unsigned short s) {
    unsigned u = ((unsigned)s) << 16;
    return __builtin_bit_cast(float, u);
}

// ---------------- prep: histograms + all weight preprocessing ----------------
// blocks 0..511: LDS histograms -> partial[which][chunk][word]
// blocks 512..647: Btc W1-part (k<40, 296..351) + Wt2 + Wt3
// blocks 648..775: Wc = Wf@W1[40:104] -> Btc k 40..295
// block 776: bias2 = bf@W1[40:104]
__global__ __launch_bounds__(256) void prep_kernel(const int* __restrict__ edge,
                                                   unsigned* __restrict__ partial,
                                                   const float* __restrict__ Wf,
                                                   const float* __restrict__ bfv,
                                                   const float* __restrict__ W1,
                                                   const float* __restrict__ W2,
                                                   const float* __restrict__ W3,
                                                   unsigned short* __restrict__ Btc,
                                                   unsigned short* __restrict__ Wt2,
                                                   unsigned short* __restrict__ Wt3,
                                                   float* __restrict__ bias2) {
    __shared__ unsigned lds[cHWORDS];
    const int b = blockIdx.x, tid = threadIdx.x;
    if (b < 512) {
        const int cb = b & (cNCHUNK - 1);
        const int half = (b >> 7) & 1;
        const int which = b >> 8;
        for (int i = tid; i < cHWORDS; i += 256) lds[i] = 0;
        __syncthreads();
        const int* ids = edge + (size_t)which * cE + (size_t)cb * cCHUNK;
        const int lo = half * (cN / 2), hi = lo + cN / 2;
        const int wbase = half * cHWORDS;
        for (int i = tid; i < cCHUNK; i += 256) {
            int v = ids[i];
            if (v >= lo && v < hi)
                atomicAdd(&lds[(v >> 1) - wbase], 1u << ((v & 1) * 16));
        }
        __syncthreads();
        unsigned* outp = partial + ((size_t)which * cNCHUNK + cb) * cWORDS + wbase;
        for (int i = tid; i < cHWORDS; i += 256) outp[i] = lds[i];
        return;
    }
    if (b < 648) {
        int i = (b - 512) * 256 + tid;
        if (i < 12288) {            // Btc: logits rows, deg rows, zero pad
            int n = i / 96, r = i - (i / 96) * 96;
            unsigned short v;
            if (r < 40)       v = f2bf(W1[r * cHID + n]);
            else if (r < 72)  v = f2bf(W1[(104 + r - 40) * cHID + n]);
            else              v = 0;
            int k = (r < 40) ? r : (r < 72 ? 296 + (r - 40) : 328 + (r - 72));
            Btc[n * cKF + k] = v;
            return;
        }
        i -= 12288;
        if (i < 16384) {            // Wt2
            int n = i >> 7, k = i & 127;
            Wt2[n * cHID + k] = f2bf(W2[k * cHID + n]);
            return;
        }
        i -= 16384;
        if (i < 6144) {             // Wt3 (48 x 128, n>=40 zero)
            int n = i >> 7, k = i & 127;
            Wt3[n * cHID + k] = (n < cNUM_CLASSES) ? f2bf(W3[k * cNUM_CLASSES + n]) : 0;
        }
        return;
    }
    if (b < 776) {                  // Wc[kf][n] = sum_j Wf[kf][j] * W1[40+j][n]
        int i = (b - 648) * 256 + tid;
        int kf = i >> 7, n = i & 127;
        float s = 0.f;
        #pragma unroll 8
        for (int j = 0; j < cFEAT_HID; ++j)
            s += Wf[kf * cFEAT_HID + j] * W1[(40 + j) * cHID + n];
        Btc[n * cKF + 40 + kf] = f2bf(s);
        return;
    }
    // bias2
    if (tid < cHID) {
        float s = 0.f;
        #pragma unroll 8
        for (int j = 0; j < cFEAT_HID; ++j)
            s += bfv[j] * W1[(40 + j) * cHID + tid];
        bias2[tid] = s;
    }
}

// ---------------- mega_scan: merge copies, chunk-prefix rewrite, rowptr, dinv, degidx ----------------
__global__ __launch_bounds__(256) void mega_scan_kernel(unsigned* __restrict__ partial,
                                                        int* __restrict__ rowptr,
                                                        float* __restrict__ dinv,
                                                        int* __restrict__ degidx,
                                                        int* __restrict__ desc) {
    const int b = blockIdx.x, tid = threadIdx.x;
    const int w = b * 256 + tid;
    unsigned slo = 0, shi = 0, plo = 0, phi = 0;
    if (w < cWORDS) {
        const unsigned* ps = partial + w;
        for (int c = 0; c < cNCHUNK; ++c) {
            unsigned v = ps[(size_t)c * cWORDS];
            slo += v & 0xFFFFu; shi += v >> 16;
        }
        unsigned* pd = partial + (size_t)cNCHUNK * cWORDS + w;
        for (int c = 0; c < cNCHUNK; ++c) {
            unsigned v = pd[(size_t)c * cWORDS];
            pd[(size_t)c * cWORDS] = plo | (phi << 16);   // per-chunk prefix (fits u16)
            plo += v & 0xFFFFu; phi += v >> 16;
        }
        int d0 = (int)(slo + plo), d1 = (int)(shi + phi);
        degidx[2 * w]     = d0 > cMAX_DEG - 1 ? cMAX_DEG - 1 : d0;
        degidx[2 * w + 1] = d1 > cMAX_DEG - 1 ? cMAX_DEG - 1 : d1;
    }
    __shared__ int s[256];
    int tot = (int)(plo + phi);
    s[tid] = tot;
    __syncthreads();
    #pragma unroll
    for (int off = 1; off < 256; off <<= 1) {
        int t = (tid >= off) ? s[tid - off] : 0;
        __syncthreads();
        s[tid] += t;
        __syncthreads();
    }
    int ex_local = s[tid] - tot;
    int block_total = s[255];
    if (tid == 0) atomicExch(&desc[b], block_total + 1);
    if (tid < b) {
        int v;
        do { v = atomicAdd(&desc[tid], 0); } while (v == 0);
        s[tid] = v - 1;
    }
    __syncthreads();
    if (tid >= b) s[tid] = 0;
    __syncthreads();
    #pragma unroll
    for (int off = 128; off > 0; off >>= 1) {
        if (tid < off) s[tid] += s[tid + off];
        __syncthreads();
    }
    int base = s[0] + ex_local;
    if (w < cWORDS) {
        rowptr[2 * w]     = base;
        rowptr[2 * w + 1] = base + (int)plo;
        dinv[2 * w]     = rsqrtf((float)(plo + 1));
        dinv[2 * w + 1] = rsqrtf((float)(phi + 1));
    }
    if (b == 0 && tid == 0) rowptr[cN] = cE;
}

// ---------------- deterministic scatter (no global atomics) ----------------
__global__ __launch_bounds__(256) void scatter2_kernel(const int* __restrict__ edge,
                                                       const unsigned* __restrict__ partial,
                                                       const int* __restrict__ rowptr,
                                                       int* __restrict__ adj) {
    __shared__ unsigned lds[cHWORDS];
    const int b = blockIdx.x, tid = threadIdx.x;
    const int cb = b & (cNCHUNK - 1);
    const int half = b >> 7;
    const int wbase = half * cHWORDS;
    const unsigned* pp = partial + ((size_t)cNCHUNK + cb) * cWORDS + wbase;
    for (int i = tid; i < cHWORDS; i += 256) lds[i] = pp[i];
    __syncthreads();
    const int* srcs = edge + (size_t)cb * cCHUNK;
    const int* dsts = edge + cE + (size_t)cb * cCHUNK;
    const int lo = half * (cN / 2), hi = lo + cN / 2;
    for (int i = tid; i < cCHUNK; i += 256) {
        int d = dsts[i];
        if (d >= lo && d < hi) {
            int sh = (d & 1) * 16;
            unsigned old = atomicAdd(&lds[(d >> 1) - wbase], 1u << sh);
            int off = (int)((old >> sh) & 0xFFFFu);
            adj[rowptr[d] + off] = srcs[i];
        }
    }
}

// ---------------- fused conv1 GEMM: t = [logits|features|deg_emb] @ Btc^T + bias2 ----------------
__global__ __launch_bounds__(256) void gemm_fused(const float* __restrict__ logits,
                                                  const float* __restrict__ features,
                                                  const float* __restrict__ deg_table,
                                                  const int* __restrict__ degidx,
                                                  const unsigned short* __restrict__ Btc,
                                                  const float* __restrict__ bias2,
                                                  unsigned short* __restrict__ out) {
    constexpr int NT = 8;
    __shared__ unsigned short As[64 * 32];
    __shared__ unsigned short Bs[NT * 16 * 32];

    const int tid = threadIdx.x;
    const int wave = tid >> 6;
    const int lane = tid & 63;
    const int m15 = lane & 15;
    const int q = lane >> 4;
    const int rowbase = blockIdx.x * 64;

    float4_t acc[NT];
    #pragma unroll
    for (int t = 0; t < NT; ++t) acc[t] = (float4_t){0.f, 0.f, 0.f, 0.f};

    const int arow = tid >> 2;
    const int akq = (tid & 3) * 8;
    int gr = rowbase + arow;
    if (gr > cN - 1) gr = cN - 1;
    const int didx = degidx[gr];

    for (int k0 = 0; k0 < cKF; k0 += 32) {
        // stage A: two float4 from the concatenated-source row (boundaries all %4)
        #pragma unroll
        for (int h = 0; h < 2; ++h) {
            int k4 = k0 + akq + h * 4;
            float4 v = make_float4(0.f, 0.f, 0.f, 0.f);
            if (k4 < 40)       v = *(const float4*)&logits[(size_t)gr * cNUM_CLASSES + k4];
            else if (k4 < 296) v = *(const float4*)&features[(size_t)gr * cFEAT_DIM + (k4 - 40)];
            else if (k4 < 328) v = *(const float4*)&deg_table[didx * cDEG_HID + (k4 - 296)];
            unsigned short* dst = &As[arow * 32 + akq + h * 4];
            dst[0] = f2bf(v.x); dst[1] = f2bf(v.y); dst[2] = f2bf(v.z); dst[3] = f2bf(v.w);
        }
        for (int i = tid; i < NT * 64; i += 256) {
            int n = i >> 2;
            int kq = (i & 3) * 8;
            *(ushort8_t*)&Bs[n * 32 + kq] = *(const ushort8_t*)&Btc[(size_t)n * cKF + k0 + kq];
        }
        __syncthreads();

        short8_t a = *(const short8_t*)&As[(wave * 16 + m15) * 32 + q * 8];
        #pragma unroll
        for (int t = 0; t < NT; ++t) {
            short8_t bfr = *(const short8_t*)&Bs[(t * 16 + m15) * 32 + q * 8];
            acc[t] = __builtin_amdgcn_mfma_f32_16x16x32_bf16(a, bfr, acc[t], 0, 0, 0);
        }
        __syncthreads();
    }

    #pragma unroll
    for (int t = 0; t < NT; ++t) {
        int col = t * 16 + m15;
        float bv = bias2[col];
        #pragma unroll
        for (int r = 0; r < 4; ++r) {
            int row = rowbase + wave * 16 + q * 4 + r;
            if (row < cN)
                out[(size_t)row * cHID + col] = f2bf(acc[t][r] + bv);
        }
    }
}

// ---------------- MFMA GEMM (bf16 A): out[m][n] = A@Bt^T, bf16 out ----------------
template <int KTOT, int NT, int OSTR, int OUTC>
__global__ __launch_bounds__(256) void mfma_gemm(const unsigned short* __restrict__ A,
                                                 const unsigned short* __restrict__ Bt,
                                                 unsigned short* __restrict__ out) {
    __shared__ unsigned short As[64 * 32];
    __shared__ unsigned short Bs[NT * 16 * 32];

    const int tid = threadIdx.x;
    const int wave = tid >> 6;
    const int lane = tid & 63;
    const int m15 = lane & 15;
    const int q = lane >> 4;
    const int rowbase = blockIdx.x * 64;

    float4_t acc[NT];
    #pragma unroll
    for (int t = 0; t < NT; ++t) acc[t] = (float4_t){0.f, 0.f, 0.f, 0.f};

    const int arow = tid >> 2;
    const int akq = (tid & 3) * 8;
    int gr = rowbase + arow;
    if (gr > cN - 1) gr = cN - 1;

    for (int k0 = 0; k0 < KTOT; k0 += 32) {
        *(ushort8_t*)&As[arow * 32 + akq] =
            *(const ushort8_t*)&A[(size_t)gr * KTOT + k0 + akq];
        for (int i = tid; i < NT * 64; i += 256) {
            int n = i >> 2;
            int kq = (i & 3) * 8;
            *(ushort8_t*)&Bs[n * 32 + kq] = *(const ushort8_t*)&Bt[(size_t)n * KTOT + k0 + kq];
        }
        __syncthreads();

        short8_t a = *(const short8_t*)&As[(wave * 16 + m15) * 32 + q * 8];
        #pragma unroll
        for (int t = 0; t < NT; ++t) {
            short8_t b = *(const short8_t*)&Bs[(t * 16 + m15) * 32 + q * 8];
            acc[t] = __builtin_amdgcn_mfma_f32_16x16x32_bf16(a, b, acc[t], 0, 0, 0);
        }
        __syncthreads();
    }

    #pragma unroll
    for (int t = 0; t < NT; ++t) {
        int col = t * 16 + m15;
        if (OUTC % 16 != 0 && col >= OUTC) continue;
        #pragma unroll
        for (int r = 0; r < 4; ++r) {
            int row = rowbase + wave * 16 + q * 4 + r;
            if (row < cN)
                out[(size_t)row * OSTR + col] = f2bf(acc[t][r]);
        }
    }
}

// ---------------- GCN aggregate over bf16 t, 128 channels -> bf16 out (R8 best config) ----------------
template <bool RELU>
__global__ __launch_bounds__(128) void agg_bf128(const unsigned short* __restrict__ t,
                                                 const int* __restrict__ rowptr,
                                                 const int* __restrict__ adj,
                                                 const float* __restrict__ dinv,
                                                 const float* __restrict__ b,
                                                 unsigned short* __restrict__ outb) {
    const int tid = threadIdx.x;
    const int lane = tid & 15;
    const int row = blockIdx.x * 8 + (tid >> 4);
    if (row >= cN) return;
    const int c = lane * 8;
    const float di = dinv[row];
    int e = rowptr[row];
    const int end = rowptr[row + 1];
    float a0[8], a1[8];
    #pragma unroll
    for (int k = 0; k < 8; ++k) { a0[k] = 0.f; a1[k] = 0.f; }
    for (; e + 1 < end; e += 2) {
        int j0 = adj[e], j1 = adj[e + 1];
        float v0 = dinv[j0], v1 = dinv[j1];
        ushort8_t t0 = *(const ushort8_t*)&t[(size_t)j0 * cHID + c];
        ushort8_t t1 = *(const ushort8_t*)&t[(size_t)j1 * cHID + c];
        #pragma unroll
        for (int k = 0; k < 8; ++k) {
            a0[k] += v0 * bf2f(t0[k]);
            a1[k] += v1 * bf2f(t1[k]);
        }
    }
    if (e < end) {
        int j0 = adj[e];
        float v0 = dinv[j0];
        ushort8_t t0 = *(const ushort8_t*)&t[(size_t)j0 * cHID + c];
        #pragma unroll
        for (int k = 0; k < 8; ++k) a0[k] += v0 * bf2f(t0[k]);
    }
    ushort8_t ts = *(const ushort8_t*)&t[(size_t)row * cHID + c];
    const float d2 = di * di;
    ushort8_t o;
    #pragma unroll
    for (int k = 0; k < 8; ++k) {
        float r = di * (a0[k] + a1[k]) + d2 * bf2f(ts[k]) + b[c + k];
        if (RELU) r = fmaxf(r, 0.f);
        o[k] = f2bf(r);
    }
    *(ushort8_t*)&outb[(size_t)row * cHID + c] = o;
}

// ---------------- GCN aggregate over bf16 t, 40 channels (final, fp32 out; R8 config) ----------------
__global__ __launch_bounds__(128) void agg_bf40(const unsigned short* __restrict__ t,
                                                const int* __restrict__ rowptr,
                                                const int* __restrict__ adj,
                                                const float* __restrict__ dinv,
                                                const float* __restrict__ b,
                                                float* __restrict__ out) {
    const int tid = threadIdx.x;
    const int lane = tid & 7;
    const int row = blockIdx.x * 16 + (tid >> 3);
    if (row >= cN) return;
    const int c = lane * 8;
    if (c >= cNUM_CLASSES) return;
    const float di = dinv[row];
    int e = rowptr[row];
    const int end = rowptr[row + 1];
    float a0[8], a1[8];
    #pragma unroll
    for (int k = 0; k < 8; ++k) { a0[k] = 0.f; a1[k] = 0.f; }
    for (; e + 1 < end; e += 2) {
        int j0 = adj[e], j1 = adj[e + 1];
        float v0 = dinv[j0], v1 = dinv[j1];
        ushort8_t t0 = *(const ushort8_t*)&t[(size_t)j0 * cNUM_CLASSES + c];
        ushort8_t t1 = *(const ushort8_t*)&t[(size_t)j1 * cNUM_CLASSES + c];
        #pragma unroll
        for (int k = 0; k < 8; ++k) {
            a0[k] += v0 * bf2f(t0[k]);
            a1[k] += v1 * bf2f(t1[k]);
        }
    }
    if (e < end) {
        int j0 = adj[e];
        float v0 = dinv[j0];
        ushort8_t t0 = *(const ushort8_t*)&t[(size_t)j0 * cNUM_CLASSES + c];
        #pragma unroll
        for (int k = 0; k < 8; ++k) a0[k] += v0 * bf2f(t0[k]);
    }
    ushort8_t ts = *(const ushort8_t*)&t[(size_t)row * cNUM_CLASSES + c];
    const float d2 = di * di;
    float r[8];
    #pragma unroll
    for (int k = 0; k < 8; ++k) r[k] = di * (a0[k] + a1[k]) + d2 * bf2f(ts[k]) + b[c + k];
    float4 v0 = make_float4(r[0], r[1], r[2], r[3]);
    float4 v1 = make_float4(r[4], r[5], r[6], r[7]);
    *(float4*)&out[(size_t)row * cNUM_CLASSES + c] = v0;
    *(float4*)&out[(size_t)row * cNUM_CLASSES + c + 4] = v1;
}

extern "C" void kernel_launch(void* const* d_in, const int* in_sizes, int n_in,
                              void* d_out, int out_size, void* d_ws, size_t ws_size,
                              hipStream_t stream) {
    const float* logits    = (const float*)d_in[0];
    const float* features  = (const float*)d_in[1];
    const int*   edge      = (const int*)d_in[2];
    const float* Wf        = (const float*)d_in[3];
    const float* bfv       = (const float*)d_in[4];
    const float* deg_table = (const float*)d_in[5];
    const float* W1        = (const float*)d_in[6];
    const float* b1        = (const float*)d_in[7];
    const float* W2        = (const float*)d_in[8];
    const float* b2        = (const float*)d_in[9];
    const float* W3        = (const float*)d_in[10];
    const float* b3        = (const float*)d_in[11];
    float* out = (float*)d_out;

    // workspace carve-up (16B-aligned sections)
    int* rowptr    = (int*)d_ws;                 // N+1 (padded)
    int* adj       = rowptr + cN + 16;           // E
    int* desc      = adj + cE;                   // 128
    int* degidx    = desc + 128;                 // N
    float* dinv    = (float*)(degidx + cN);      // N
    float* bias2   = dinv + cN;                  // 128
    unsigned short* tb  = (unsigned short*)(bias2 + 128);          // N*128 bf16
    unsigned short* hb  = tb + (size_t)cN * cHID;                  // N*128 bf16
    unsigned short* Btc = hb + (size_t)cN * cHID;                  // 128*352
    unsigned short* Wt2 = Btc + 128 * cKF;                         // 128*128
    unsigned short* Wt3 = Wt2 + 128 * cHID;                        // 48*128
    unsigned* partial = (unsigned*)(Wt3 + 48 * cHID);              // 2*128*25000 u32

    hipMemsetAsync(desc, 0, 128 * sizeof(int), stream);

    // histograms + all weight preprocessing (one launch, 777 blocks)
    prep_kernel<<<777, 256, 0, stream>>>(edge, partial, Wf, bfv, W1, W2, W3,
                                         Btc, Wt2, Wt3, bias2);

    // merged scan: chunk-prefix rewrite, rowptr, dinv, degidx (one launch, parallel lookback)
    mega_scan_kernel<<<cSCANB, 256, 0, stream>>>(partial, rowptr, dinv, degidx, desc);

    // CSR scatter (no global atomics)
    scatter2_kernel<<<256, 256, 0, stream>>>(edge, partial, rowptr, adj);

    constexpr int MB = (cN + 63) / 64; // 782

    // conv1 (fused frontend): tb = bf16([logits|feat|deg_emb] @ Btc^T + bias2)
    gemm_fused<<<MB, 256, 0, stream>>>(logits, features, deg_table, degidx, Btc, bias2, tb);
    agg_bf128<true><<<(cN + 7) / 8, 128, 0, stream>>>(tb, rowptr, adj, dinv, b1, hb);

    // conv2
    mfma_gemm<cHID, 8, cHID, cHID><<<MB, 256, 0, stream>>>(hb, Wt2, tb);
    agg_bf128<true><<<(cN + 7) / 8, 128, 0, stream>>>(tb, rowptr, adj, dinv, b2, hb);

    // conv3
    mfma_gemm<cHID, 3, cNUM_CLASSES, cNUM_CLASSES><<<MB, 256, 0, stream>>>(hb, Wt3, tb);
    agg_bf40<<<(cN + 15) / 16, 128, 0, stream>>>(tb, rowptr, adj, dinv, b3, out);
}

// Round 12
// 287.455 us; speedup vs baseline: 1.2735x; 1.0210x over previous
//
#include <hip/hip_runtime.h>
#include <hip/hip_bf16.h>

// Problem constants (match reference)
constexpr int cN = 50000;
constexpr int cE = 800000;
constexpr int cNUM_CLASSES = 40;
constexpr int cFEAT_DIM = 256;
constexpr int cFEAT_HID = 64;
constexpr int cDEG_HID = 32;
constexpr int cHID = 128;
constexpr int cMAX_DEG = 256;
constexpr int cKF = 352;                // fused conv1 K: 40 logits + 256 feat + 32 deg + 24 pad

// LDS-histogram CSR build parameters
constexpr int cNCHUNK = 64;             // edge chunks (= copies per histogram)
constexpr int cCHUNK  = cE / cNCHUNK;   // 12500 edges per chunk (exact)
constexpr int cWORDS  = cN / 2;         // 25000 packed u16-pair words per histogram
constexpr int cHWORDS = cWORDS / 2;     // 12500 words per node-range half (50 KB LDS)
constexpr int cSCANB  = (cWORDS + 255) / 256; // 98 blocks for mega_scan

typedef unsigned short ushort8_t __attribute__((ext_vector_type(8)));
typedef short short8_t __attribute__((ext_vector_type(8)));
typedef float float4_t __attribute__((ext_vector_type(4)));

__device__ __forceinline__ unsigned short f2bf(float f) {
    unsigned u = __builtin_bit_cast(unsigned, f);
    u += 0x7fff + ((u >> 16) & 1); // RNE
    return (unsigned short)(u >> 16);
}
__device__ __forceinline__ float bf2f(unsigned short s) {
    unsigned u = ((unsigned)s) << 16;
    return __builtin_bit_cast(float, u);
}

// ---------------- prep: histograms + all weight preprocessing + desc init ----------------
// blocks 0..255:   LDS histograms -> partial[which][chunk][word]  (cb=b&63, half=(b>>6)&1, which=b>>7)
// blocks 256..391: Btc W1-part (k<40, 296..351) + Wt2 + Wt3
// blocks 392..455: Wc = Wf@W1[40:104] -> Btc k 40..295
// block 456:       bias2 = bf@W1[40:104] ; desc[0..97] = 0
__global__ __launch_bounds__(256) void prep_kernel(const int* __restrict__ edge,
                                                   unsigned* __restrict__ partial,
                                                   const float* __restrict__ Wf,
                                                   const float* __restrict__ bfv,
                                                   const float* __restrict__ W1,
                                                   const float* __restrict__ W2,
                                                   const float* __restrict__ W3,
                                                   unsigned short* __restrict__ Btc,
                                                   unsigned short* __restrict__ Wt2,
                                                   unsigned short* __restrict__ Wt3,
                                                   float* __restrict__ bias2,
                                                   int* __restrict__ desc) {
    __shared__ unsigned lds[cHWORDS];
    const int b = blockIdx.x, tid = threadIdx.x;
    if (b < 256) {
        const int cb = b & (cNCHUNK - 1);
        const int half = (b >> 6) & 1;
        const int which = b >> 7;
        for (int i = tid; i < cHWORDS; i += 256) lds[i] = 0;
        __syncthreads();
        const int* ids = edge + (size_t)which * cE + (size_t)cb * cCHUNK;
        const int lo = half * (cN / 2), hi = lo + cN / 2;
        const int wbase = half * cHWORDS;
        for (int i = tid; i < cCHUNK; i += 256) {
            int v = ids[i];
            if (v >= lo && v < hi)
                atomicAdd(&lds[(v >> 1) - wbase], 1u << ((v & 1) * 16));
        }
        __syncthreads();
        unsigned* outp = partial + ((size_t)which * cNCHUNK + cb) * cWORDS + wbase;
        for (int i = tid; i < cHWORDS; i += 256) outp[i] = lds[i];
        return;
    }
    if (b < 392) {
        int i = (b - 256) * 256 + tid;
        if (i < 12288) {            // Btc: logits rows, deg rows, zero pad
            int n = i / 96, r = i - (i / 96) * 96;
            unsigned short v;
            if (r < 40)       v = f2bf(W1[r * cHID + n]);
            else if (r < 72)  v = f2bf(W1[(104 + r - 40) * cHID + n]);
            else              v = 0;
            int k = (r < 40) ? r : (r < 72 ? 296 + (r - 40) : 328 + (r - 72));
            Btc[n * cKF + k] = v;
            return;
        }
        i -= 12288;
        if (i < 16384) {            // Wt2
            int n = i >> 7, k = i & 127;
            Wt2[n * cHID + k] = f2bf(W2[k * cHID + n]);
            return;
        }
        i -= 16384;
        if (i < 6144) {             // Wt3 (48 x 128, n>=40 zero)
            int n = i >> 7, k = i & 127;
            Wt3[n * cHID + k] = (n < cNUM_CLASSES) ? f2bf(W3[k * cNUM_CLASSES + n]) : 0;
        }
        return;
    }
    if (b < 456) {                  // Wc[kf][n] = sum_j Wf[kf][j] * W1[40+j][n]
        int i = (b - 392) * 256 + tid;
        int kf = i >> 7, n = i & 127;
        float s = 0.f;
        #pragma unroll 8
        for (int j = 0; j < cFEAT_HID; ++j)
            s += Wf[kf * cFEAT_HID + j] * W1[(40 + j) * cHID + n];
        Btc[n * cKF + 40 + kf] = f2bf(s);
        return;
    }
    // bias2 + desc init
    if (tid < cHID) {
        float s = 0.f;
        #pragma unroll 8
        for (int j = 0; j < cFEAT_HID; ++j)
            s += bfv[j] * W1[(40 + j) * cHID + tid];
        bias2[tid] = s;
    } else if (tid - 128 < cSCANB) {
        desc[tid - 128] = 0;
    }
}

// ---------------- mega_scan: merge copies, chunk-prefix rewrite, rowptr, dinv, degidx ----------------
__global__ __launch_bounds__(256) void mega_scan_kernel(unsigned* __restrict__ partial,
                                                        int* __restrict__ rowptr,
                                                        float* __restrict__ dinv,
                                                        int* __restrict__ degidx,
                                                        int* __restrict__ desc) {
    const int b = blockIdx.x, tid = threadIdx.x;
    const int w = b * 256 + tid;
    unsigned slo = 0, shi = 0, plo = 0, phi = 0;
    if (w < cWORDS) {
        const unsigned* ps = partial + w;
        for (int c = 0; c < cNCHUNK; ++c) {
            unsigned v = ps[(size_t)c * cWORDS];
            slo += v & 0xFFFFu; shi += v >> 16;
        }
        unsigned* pd = partial + (size_t)cNCHUNK * cWORDS + w;
        for (int c = 0; c < cNCHUNK; ++c) {
            unsigned v = pd[(size_t)c * cWORDS];
            pd[(size_t)c * cWORDS] = plo | (phi << 16);   // per-chunk prefix (fits u16)
            plo += v & 0xFFFFu; phi += v >> 16;
        }
        int d0 = (int)(slo + plo), d1 = (int)(shi + phi);
        degidx[2 * w]     = d0 > cMAX_DEG - 1 ? cMAX_DEG - 1 : d0;
        degidx[2 * w + 1] = d1 > cMAX_DEG - 1 ? cMAX_DEG - 1 : d1;
    }
    __shared__ int s[256];
    int tot = (int)(plo + phi);
    s[tid] = tot;
    __syncthreads();
    #pragma unroll
    for (int off = 1; off < 256; off <<= 1) {
        int t = (tid >= off) ? s[tid - off] : 0;
        __syncthreads();
        s[tid] += t;
        __syncthreads();
    }
    int ex_local = s[tid] - tot;
    int block_total = s[255];
    if (tid == 0) atomicExch(&desc[b], block_total + 1);
    if (tid < b) {
        int v;
        do { v = atomicAdd(&desc[tid], 0); } while (v == 0);
        s[tid] = v - 1;
    }
    __syncthreads();
    if (tid >= b) s[tid] = 0;
    __syncthreads();
    #pragma unroll
    for (int off = 128; off > 0; off >>= 1) {
        if (tid < off) s[tid] += s[tid + off];
        __syncthreads();
    }
    int base = s[0] + ex_local;
    if (w < cWORDS) {
        rowptr[2 * w]     = base;
        rowptr[2 * w + 1] = base + (int)plo;
        dinv[2 * w]     = rsqrtf((float)(plo + 1));
        dinv[2 * w + 1] = rsqrtf((float)(phi + 1));
    }
    if (b == 0 && tid == 0) rowptr[cN] = cE;
}

// ---------------- merged: CSR scatter (blocks 0..127) + fused conv1 GEMM (blocks 128..909) ----------------
__global__ __launch_bounds__(256) void scatter_gemm_kernel(const int* __restrict__ edge,
                                                           const unsigned* __restrict__ partial,
                                                           const int* __restrict__ rowptr,
                                                           int* __restrict__ adj,
                                                           const float* __restrict__ logits,
                                                           const float* __restrict__ features,
                                                           const float* __restrict__ deg_table,
                                                           const int* __restrict__ degidx,
                                                           const unsigned short* __restrict__ Btc,
                                                           const float* __restrict__ bias2,
                                                           unsigned short* __restrict__ out) {
    __shared__ unsigned shmem[cHWORDS];   // 50 KB, shared by both roles
    const int b = blockIdx.x, tid = threadIdx.x;

    if (b < 128) {
        // ---- scatter role ----
        const int cb = b & (cNCHUNK - 1);
        const int half = (b >> 6) & 1;
        const int wbase = half * cHWORDS;
        const unsigned* pp = partial + ((size_t)cNCHUNK + cb) * cWORDS + wbase;
        for (int i = tid; i < cHWORDS; i += 256) shmem[i] = pp[i];
        __syncthreads();
        const int* srcs = edge + (size_t)cb * cCHUNK;
        const int* dsts = edge + cE + (size_t)cb * cCHUNK;
        const int lo = half * (cN / 2), hi = lo + cN / 2;
        for (int i = tid; i < cCHUNK; i += 256) {
            int d = dsts[i];
            if (d >= lo && d < hi) {
                int sh = (d & 1) * 16;
                unsigned old = atomicAdd(&shmem[(d >> 1) - wbase], 1u << sh);
                int off = (int)((old >> sh) & 0xFFFFu);
                adj[rowptr[d] + off] = srcs[i];
            }
        }
        return;
    }

    // ---- fused conv1 GEMM role ----
    constexpr int NT = 8;
    unsigned short* As = (unsigned short*)shmem;        // 64*32
    unsigned short* Bs = As + 64 * 32;                  // NT*16*32

    const int gb = b - 128;
    const int wave = tid >> 6;
    const int lane = tid & 63;
    const int m15 = lane & 15;
    const int q = lane >> 4;
    const int rowbase = gb * 64;

    float4_t acc[NT];
    #pragma unroll
    for (int t = 0; t < NT; ++t) acc[t] = (float4_t){0.f, 0.f, 0.f, 0.f};

    const int arow = tid >> 2;
    const int akq = (tid & 3) * 8;
    int gr = rowbase + arow;
    if (gr > cN - 1) gr = cN - 1;
    const int didx = degidx[gr];

    for (int k0 = 0; k0 < cKF; k0 += 32) {
        #pragma unroll
        for (int h = 0; h < 2; ++h) {
            int k4 = k0 + akq + h * 4;
            float4 v = make_float4(0.f, 0.f, 0.f, 0.f);
            if (k4 < 40)       v = *(const float4*)&logits[(size_t)gr * cNUM_CLASSES + k4];
            else if (k4 < 296) v = *(const float4*)&features[(size_t)gr * cFEAT_DIM + (k4 - 40)];
            else if (k4 < 328) v = *(const float4*)&deg_table[didx * cDEG_HID + (k4 - 296)];
            unsigned short* dst = &As[arow * 32 + akq + h * 4];
            dst[0] = f2bf(v.x); dst[1] = f2bf(v.y); dst[2] = f2bf(v.z); dst[3] = f2bf(v.w);
        }
        for (int i = tid; i < NT * 64; i += 256) {
            int n = i >> 2;
            int kq = (i & 3) * 8;
            *(ushort8_t*)&Bs[n * 32 + kq] = *(const ushort8_t*)&Btc[(size_t)n * cKF + k0 + kq];
        }
        __syncthreads();

        short8_t a = *(const short8_t*)&As[(wave * 16 + m15) * 32 + q * 8];
        #pragma unroll
        for (int t = 0; t < NT; ++t) {
            short8_t bfr = *(const short8_t*)&Bs[(t * 16 + m15) * 32 + q * 8];
            acc[t] = __builtin_amdgcn_mfma_f32_16x16x32_bf16(a, bfr, acc[t], 0, 0, 0);
        }
        __syncthreads();
    }

    #pragma unroll
    for (int t = 0; t < NT; ++t) {
        int col = t * 16 + m15;
        float bv = bias2[col];
        #pragma unroll
        for (int r = 0; r < 4; ++r) {
            int row = rowbase + wave * 16 + q * 4 + r;
            if (row < cN)
                out[(size_t)row * cHID + col] = f2bf(acc[t][r] + bv);
        }
    }
}

// ---------------- MFMA GEMM (bf16 A): out[m][n] = A@Bt^T, bf16 out ----------------
template <int KTOT, int NT, int OSTR, int OUTC>
__global__ __launch_bounds__(256) void mfma_gemm(const unsigned short* __restrict__ A,
                                                 const unsigned short* __restrict__ Bt,
                                                 unsigned short* __restrict__ out) {
    __shared__ unsigned short As[64 * 32];
    __shared__ unsigned short Bs[NT * 16 * 32];

    const int tid = threadIdx.x;
    const int wave = tid >> 6;
    const int lane = tid & 63;
    const int m15 = lane & 15;
    const int q = lane >> 4;
    const int rowbase = blockIdx.x * 64;

    float4_t acc[NT];
    #pragma unroll
    for (int t = 0; t < NT; ++t) acc[t] = (float4_t){0.f, 0.f, 0.f, 0.f};

    const int arow = tid >> 2;
    const int akq = (tid & 3) * 8;
    int gr = rowbase + arow;
    if (gr > cN - 1) gr = cN - 1;

    for (int k0 = 0; k0 < KTOT; k0 += 32) {
        *(ushort8_t*)&As[arow * 32 + akq] =
            *(const ushort8_t*)&A[(size_t)gr * KTOT + k0 + akq];
        for (int i = tid; i < NT * 64; i += 256) {
            int n = i >> 2;
            int kq = (i & 3) * 8;
            *(ushort8_t*)&Bs[n * 32 + kq] = *(const ushort8_t*)&Bt[(size_t)n * KTOT + k0 + kq];
        }
        __syncthreads();

        short8_t a = *(const short8_t*)&As[(wave * 16 + m15) * 32 + q * 8];
        #pragma unroll
        for (int t = 0; t < NT; ++t) {
            short8_t b = *(const short8_t*)&Bs[(t * 16 + m15) * 32 + q * 8];
            acc[t] = __builtin_amdgcn_mfma_f32_16x16x32_bf16(a, b, acc[t], 0, 0, 0);
        }
        __syncthreads();
    }

    #pragma unroll
    for (int t = 0; t < NT; ++t) {
        int col = t * 16 + m15;
        if (OUTC % 16 != 0 && col >= OUTC) continue;
        #pragma unroll
        for (int r = 0; r < 4; ++r) {
            int row = rowbase + wave * 16 + q * 4 + r;
            if (row < cN)
                out[(size_t)row * OSTR + col] = f2bf(acc[t][r]);
        }
    }
}

// ---------------- GCN aggregate over bf16 t, 128 channels -> bf16 out (R8 best config) ----------------
template <bool RELU>
__global__ __launch_bounds__(128) void agg_bf128(const unsigned short* __restrict__ t,
                                                 const int* __restrict__ rowptr,
                                                 const int* __restrict__ adj,
                                                 const float* __restrict__ dinv,
                                                 const float* __restrict__ b,
                                                 unsigned short* __restrict__ outb) {
    const int tid = threadIdx.x;
    const int lane = tid & 15;
    const int row = blockIdx.x * 8 + (tid >> 4);
    if (row >= cN) return;
    const int c = lane * 8;
    const float di = dinv[row];
    int e = rowptr[row];
    const int end = rowptr[row + 1];
    float a0[8], a1[8];
    #pragma unroll
    for (int k = 0; k < 8; ++k) { a0[k] = 0.f; a1[k] = 0.f; }
    for (; e + 1 < end; e += 2) {
        int j0 = adj[e], j1 = adj[e + 1];
        float v0 = dinv[j0], v1 = dinv[j1];
        ushort8_t t0 = *(const ushort8_t*)&t[(size_t)j0 * cHID + c];
        ushort8_t t1 = *(const ushort8_t*)&t[(size_t)j1 * cHID + c];
        #pragma unroll
        for (int k = 0; k < 8; ++k) {
            a0[k] += v0 * bf2f(t0[k]);
            a1[k] += v1 * bf2f(t1[k]);
        }
    }
    if (e < end) {
        int j0 = adj[e];
        float v0 = dinv[j0];
        ushort8_t t0 = *(const ushort8_t*)&t[(size_t)j0 * cHID + c];
        #pragma unroll
        for (int k = 0; k < 8; ++k) a0[k] += v0 * bf2f(t0[k]);
    }
    ushort8_t ts = *(const ushort8_t*)&t[(size_t)row * cHID + c];
    const float d2 = di * di;
    ushort8_t o;
    #pragma unroll
    for (int k = 0; k < 8; ++k) {
        float r = di * (a0[k] + a1[k]) + d2 * bf2f(ts[k]) + b[c + k];
        if (RELU) r = fmaxf(r, 0.f);
        o[k] = f2bf(r);
    }
    *(ushort8_t*)&outb[(size_t)row * cHID + c] = o;
}

// ---------------- GCN aggregate over bf16 t, 40 channels (final, fp32 out; R8 config) ----------------
__global__ __launch_bounds__(128) void agg_bf40(const unsigned short* __restrict__ t,
                                                const int* __restrict__ rowptr,
                                                const int* __restrict__ adj,
                                                const float* __restrict__ dinv,
                                                const float* __restrict__ b,
                                                float* __restrict__ out) {
    const int tid = threadIdx.x;
    const int lane = tid & 7;
    const int row = blockIdx.x * 16 + (tid >> 3);
    if (row >= cN) return;
    const int c = lane * 8;
    if (c >= cNUM_CLASSES) return;
    const float di = dinv[row];
    int e = rowptr[row];
    const int end = rowptr[row + 1];
    float a0[8], a1[8];
    #pragma unroll
    for (int k = 0; k < 8; ++k) { a0[k] = 0.f; a1[k] = 0.f; }
    for (; e + 1 < end; e += 2) {
        int j0 = adj[e], j1 = adj[e + 1];
        float v0 = dinv[j0], v1 = dinv[j1];
        ushort8_t t0 = *(const ushort8_t*)&t[(size_t)j0 * cNUM_CLASSES + c];
        ushort8_t t1 = *(const ushort8_t*)&t[(size_t)j1 * cNUM_CLASSES + c];
        #pragma unroll
        for (int k = 0; k < 8; ++k) {
            a0[k] += v0 * bf2f(t0[k]);
            a1[k] += v1 * bf2f(t1[k]);
        }
    }
    if (e < end) {
        int j0 = adj[e];
        float v0 = dinv[j0];
        ushort8_t t0 = *(const ushort8_t*)&t[(size_t)j0 * cNUM_CLASSES + c];
        #pragma unroll
        for (int k = 0; k < 8; ++k) a0[k] += v0 * bf2f(t0[k]);
    }
    ushort8_t ts = *(const ushort8_t*)&t[(size_t)row * cNUM_CLASSES + c];
    const float d2 = di * di;
    float r[8];
    #pragma unroll
    for (int k = 0; k < 8; ++k) r[k] = di * (a0[k] + a1[k]) + d2 * bf2f(ts[k]) + b[c + k];
    float4 v0 = make_float4(r[0], r[1], r[2], r[3]);
    float4 v1 = make_float4(r[4], r[5], r[6], r[7]);
    *(float4*)&out[(size_t)row * cNUM_CLASSES + c] = v0;
    *(float4*)&out[(size_t)row * cNUM_CLASSES + c + 4] = v1;
}

extern "C" void kernel_launch(void* const* d_in, const int* in_sizes, int n_in,
                              void* d_out, int out_size, void* d_ws, size_t ws_size,
                              hipStream_t stream) {
    const float* logits    = (const float*)d_in[0];
    const float* features  = (const float*)d_in[1];
    const int*   edge      = (const int*)d_in[2];
    const float* Wf        = (const float*)d_in[3];
    const float* bfv       = (const float*)d_in[4];
    const float* deg_table = (const float*)d_in[5];
    const float* W1        = (const float*)d_in[6];
    const float* b1        = (const float*)d_in[7];
    const float* W2        = (const float*)d_in[8];
    const float* b2        = (const float*)d_in[9];
    const float* W3        = (const float*)d_in[10];
    const float* b3        = (const float*)d_in[11];
    float* out = (float*)d_out;

    // workspace carve-up (16B-aligned sections)
    int* rowptr    = (int*)d_ws;                 // N+1 (padded)
    int* adj       = rowptr + cN + 16;           // E
    int* desc      = adj + cE;                   // 128
    int* degidx    = desc + 128;                 // N
    float* dinv    = (float*)(degidx + cN);      // N
    float* bias2   = dinv + cN;                  // 128
    unsigned short* tb  = (unsigned short*)(bias2 + 128);          // N*128 bf16
    unsigned short* hb  = tb + (size_t)cN * cHID;                  // N*128 bf16
    unsigned short* Btc = hb + (size_t)cN * cHID;                  // 128*352
    unsigned short* Wt2 = Btc + 128 * cKF;                         // 128*128
    unsigned short* Wt3 = Wt2 + 128 * cHID;                        // 48*128
    unsigned* partial = (unsigned*)(Wt3 + 48 * cHID);              // 2*64*25000 u32

    // histograms + all weight preprocessing + desc init (one launch, 457 blocks)
    prep_kernel<<<457, 256, 0, stream>>>(edge, partial, Wf, bfv, W1, W2, W3,
                                         Btc, Wt2, Wt3, bias2, desc);

    // merged scan: chunk-prefix rewrite, rowptr, dinv, degidx (one launch, parallel lookback)
    mega_scan_kernel<<<cSCANB, 256, 0, stream>>>(partial, rowptr, dinv, degidx, desc);

    constexpr int MB = (cN + 63) / 64; // 782

    // merged: CSR scatter (128 blocks) + fused conv1 GEMM (782 blocks)
    scatter_gemm_kernel<<<128 + MB, 256, 0, stream>>>(edge, partial, rowptr, adj,
                                                      logits, features, deg_table, degidx,
                                                      Btc, bias2, tb);
    agg_bf128<true><<<(cN + 7) / 8, 128, 0, stream>>>(tb, rowptr, adj, dinv, b1, hb);

    // conv2
    mfma_gemm<cHID, 8, cHID, cHID><<<MB, 256, 0, stream>>>(hb, Wt2, tb);
    agg_bf128<true><<<(cN + 7) / 8, 128, 0, stream>>>(tb, rowptr, adj, dinv, b2, hb);

    // conv3
    mfma_gemm<cHID, 3, cNUM_CLASSES, cNUM_CLASSES><<<MB, 256, 0, stream>>>(hb, Wt3, tb);
    agg_bf40<<<(cN + 15) / 16, 128, 0, stream>>>(tb, rowptr, adj, dinv, b3, out);
}